// Round 2
// baseline (273.002 us; speedup 1.0000x reference)
//
#include <hip/hip_runtime.h>

// Problem constants (match reference)
#define HH 480
#define WW 640
#define HP 30
#define WP 40
#define NP (HP * WP)   // 1200 points per batch
#define BB 128
#define DENSE_N ((size_t)BB * HH * WW)   // 39,321,600 floats

// Grid-stride float4 zero-fill: 157 MB of pure coalesced 16B stores.
__global__ __launch_bounds__(256) void zero_fill_kernel(float4* __restrict__ p, int n4) {
    int stride = gridDim.x * blockDim.x;
    const float4 z = make_float4(0.f, 0.f, 0.f, 0.f);
    for (int i = blockIdx.x * blockDim.x + threadIdx.x; i < n4; i += stride)
        p[i] = z;
}

// One thread per sample point: grid output + bilinear sample + scatter-add.
// Grid: x = point tiles, y = batch (no integer division).
__global__ __launch_bounds__(256) void sample_scatter_kernel(
    const float* __restrict__ pooled,   // [B, 2, HP, WP]
    const float* __restrict__ depth,    // [B, 1, H, W]
    float* __restrict__ sparse,         // [B, 1, H, W] (pre-zeroed)
    float2* __restrict__ grid_out)      // [B, HP, WP, 2]
{
    int p = blockIdx.x * blockDim.x + threadIdx.x;
    int b = blockIdx.y;
    if (p >= NP) return;

    float gx = pooled[(size_t)b * 2 * NP + p];        // channel 0 = x
    float gy = pooled[(size_t)b * 2 * NP + NP + p];   // channel 1 = y

    // grid_to_sample (second output), reference arithmetic order
    float grid_w = (2.0f * gx - (float)WW) / (float)WW;
    float grid_h = (2.0f * gy - (float)HH) / (float)HH;
    grid_out[(size_t)b * NP + p] = make_float2(grid_w, grid_h);

    // Bilinear sample, align_corners=True, zeros padding — replicate the
    // reference's normalization round-trip arithmetic exactly.
    float x = (grid_w + 1.0f) * 0.5f * (float)(WW - 1);
    float y = (grid_h + 1.0f) * 0.5f * (float)(HH - 1);
    float x0f = floorf(x), y0f = floorf(y);
    float wx1 = x - x0f, wx0 = 1.0f - wx1;
    float wy1 = y - y0f, wy0 = 1.0f - wy1;
    int x0 = (int)x0f, y0 = (int)y0f;
    int x1 = x0 + 1,  y1 = y0 + 1;

    const float* img = depth + (size_t)b * HH * WW;

    float v00 = (y0 >= 0 && y0 <= HH - 1 && x0 >= 0 && x0 <= WW - 1) ? img[y0 * WW + x0] : 0.0f;
    float v01 = (y0 >= 0 && y0 <= HH - 1 && x1 >= 0 && x1 <= WW - 1) ? img[y0 * WW + x1] : 0.0f;
    float v10 = (y1 >= 0 && y1 <= HH - 1 && x0 >= 0 && x0 <= WW - 1) ? img[y1 * WW + x0] : 0.0f;
    float v11 = (y1 >= 0 && y1 <= HH - 1 && x1 >= 0 && x1 <= WW - 1) ? img[y1 * WW + x1] : 0.0f;

    float v = v00 * wy0 * wx0 + v01 * wy0 * wx1 + v10 * wy1 * wx0 + v11 * wy1 * wx1;

    // rows/cols: round half-to-even (jnp.round == rintf) THEN clip
    float ry = rintf(gy), rx = rintf(gx);
    int row = (int)fminf(fmaxf(ry, 0.0f), (float)(HH - 1));
    int col = (int)fminf(fmaxf(rx, 0.0f), (float)(WW - 1));

    atomicAdd(&sparse[(size_t)b * HH * WW + row * WW + col], v);
}

extern "C" void kernel_launch(void* const* d_in, const int* in_sizes, int n_in,
                              void* d_out, int out_size, void* d_ws, size_t ws_size,
                              hipStream_t stream) {
    const float* pooled = (const float*)d_in[0];   // [B,2,HP,WP] fp32
    const float* depth  = (const float*)d_in[1];   // [B,1,H,W]  fp32

    float* out = (float*)d_out;
    float* sparse = out;                                   // output 0: B*H*W floats
    float2* grid_out = (float2*)(out + DENSE_N);           // output 1: B*NP float2

    // Zero the dense image with clean vectorized stores (d_out is re-poisoned
    // to 0xAA before every timed launch).
    int n4 = (int)(DENSE_N / 4);                           // 9,830,400 float4s
    zero_fill_kernel<<<2048, 256, 0, stream>>>((float4*)sparse, n4);

    dim3 grid((NP + 255) / 256, BB);
    sample_scatter_kernel<<<grid, 256, 0, stream>>>(pooled, depth, sparse, grid_out);
}

// Round 3
// 270.057 us; speedup vs baseline: 1.0109x; 1.0109x over previous
//
#include <hip/hip_runtime.h>

// Problem constants (match reference)
#define HH 480
#define WW 640
#define HP 30
#define WP 40
#define NP (HP * WP)      // 1200 points per batch
#define BB 128
#define DENSE_N ((size_t)BB * HH * WW)   // 39,321,600 floats

#define TILE_FLOATS 4096                  // 16 KB LDS tile
#define TILES_PER_B (HH * WW / TILE_FLOATS)   // 75

// Fused: zero + gather-formulated scatter + grid output, one kernel.
// Block (t, b): owns flat range [t*4096, (t+1)*4096) of batch b's image.
__global__ __launch_bounds__(256) void fused_sparse_depth_kernel(
    const float* __restrict__ pooled,   // [B, 2, HP, WP]
    const float* __restrict__ depth,    // [B, 1, H, W]
    float* __restrict__ sparse,         // [B, 1, H, W]
    float2* __restrict__ grid_out)      // [B, HP, WP, 2]
{
    __shared__ float tile[TILE_FLOATS];
    const int t   = blockIdx.x;   // tile index within batch
    const int b   = blockIdx.y;   // batch
    const int tid = threadIdx.x;

    // Zero the LDS tile (conflict-free: lane i -> consecutive addresses).
    #pragma unroll
    for (int i = tid; i < TILE_FLOATS; i += 256) tile[i] = 0.0f;
    __syncthreads();

    const int base = t * TILE_FLOATS;            // flat offset within image
    const float* px  = pooled + (size_t)b * 2 * NP;        // channel 0 = x
    const float* py  = px + NP;                            // channel 1 = y
    const float* img = depth + (size_t)b * HH * WW;

    for (int p = tid; p < NP; p += 256) {
        float gx = px[p];
        float gy = py[p];

        // grid_to_sample (output 1), reference arithmetic order
        float grid_w = (2.0f * gx - (float)WW) / (float)WW;
        float grid_h = (2.0f * gy - (float)HH) / (float)HH;
        if (t == 0) grid_out[(size_t)b * NP + p] = make_float2(grid_w, grid_h);

        // Destination: round half-to-even (jnp.round == rintf) THEN clip.
        float ry = rintf(gy), rx = rintf(gx);
        int row = (int)fminf(fmaxf(ry, 0.0f), (float)(HH - 1));
        int col = (int)fminf(fmaxf(rx, 0.0f), (float)(WW - 1));
        int loc = row * WW + col - base;

        if (loc >= 0 && loc < TILE_FLOATS) {
            // Bilinear sample (align_corners=True, zeros padding) — replicate
            // the reference's normalization round-trip exactly.
            float x = (grid_w + 1.0f) * 0.5f * (float)(WW - 1);
            float y = (grid_h + 1.0f) * 0.5f * (float)(HH - 1);
            float x0f = floorf(x), y0f = floorf(y);
            float wx1 = x - x0f, wx0 = 1.0f - wx1;
            float wy1 = y - y0f, wy0 = 1.0f - wy1;
            int x0 = (int)x0f, y0 = (int)y0f;
            int x1 = x0 + 1,  y1 = y0 + 1;

            float v00 = (y0 >= 0 && y0 <= HH - 1 && x0 >= 0 && x0 <= WW - 1) ? img[y0 * WW + x0] : 0.0f;
            float v01 = (y0 >= 0 && y0 <= HH - 1 && x1 >= 0 && x1 <= WW - 1) ? img[y0 * WW + x1] : 0.0f;
            float v10 = (y1 >= 0 && y1 <= HH - 1 && x0 >= 0 && x0 <= WW - 1) ? img[y1 * WW + x0] : 0.0f;
            float v11 = (y1 >= 0 && y1 <= HH - 1 && x1 >= 0 && x1 <= WW - 1) ? img[y1 * WW + x1] : 0.0f;

            float v = v00 * wy0 * wx0 + v01 * wy0 * wx1 + v10 * wy1 * wx0 + v11 * wy1 * wx1;
            atomicAdd(&tile[loc], v);
        }
    }
    __syncthreads();

    // Stream the tile to global: 1024 float4, fully coalesced.
    float4* dst = (float4*)(sparse + (size_t)b * HH * WW + base);
    const float4* src = (const float4*)tile;
    #pragma unroll
    for (int i = tid; i < TILE_FLOATS / 4; i += 256) dst[i] = src[i];
}

extern "C" void kernel_launch(void* const* d_in, const int* in_sizes, int n_in,
                              void* d_out, int out_size, void* d_ws, size_t ws_size,
                              hipStream_t stream) {
    const float* pooled = (const float*)d_in[0];   // [B,2,HP,WP] fp32
    const float* depth  = (const float*)d_in[1];   // [B,1,H,W]  fp32

    float* out = (float*)d_out;
    float* sparse = out;                            // output 0: B*H*W floats
    float2* grid_out = (float2*)(out + DENSE_N);    // output 1: B*NP float2

    dim3 grid(TILES_PER_B, BB);                     // 75 x 128 = 9600 blocks
    fused_sparse_depth_kernel<<<grid, 256, 0, stream>>>(pooled, depth, sparse, grid_out);
}